// Round 15
// baseline (71.513 us; speedup 1.0000x reference)
//
#include <hip/hip_runtime.h>

typedef unsigned short u16;
typedef __attribute__((ext_vector_type(8))) short short8;
typedef __attribute__((ext_vector_type(4))) float f32x4;

#define MFMA16(a, b, c) __builtin_amdgcn_mfma_f32_16x16x32_bf16((a), (b), (c), 0, 0, 0)

__device__ __forceinline__ u16 f2bf(float f) {
    unsigned u = __float_as_uint(f);
    unsigned r = (u + 0x7FFFu + ((u >> 16) & 1u)) >> 16;
    return (u16)r;
}

__device__ const float MAXV[22] = {9.f, 1.f, 1.f, 10.f, 3.f, 254.f, 1.f, 1.f, 235.f, 8.f, 9.f,
                                   250.f, 29.f, 1.f, 1.f, 8.f, 1.f, 1.f, 6.f, 3.f, 1.f, 2.f};

// ---------------- prep: all weights -> bf16 MFMA-fragment layouts, 1/MAX folded ----------------
__global__ void prep_kernel(
    const float* c1w, const float* c1b, const float* c2w, const float* c2b,
    const float* fcw, const float* fcb, const float* sfw, const float* sfb,
    const float* a0w, const float* a0b, const float* a1w, const float* a1b,
    const float* vw, const float* vb,
    u16* W1F, u16* W2F, u16* FCF, u16* SELFF, u16* HEADF, float* BIAS)
{
    int idx = blockIdx.x * 256 + threadIdx.x;
    if (idx < 73728) {                       // W1F: grp = g*18+ks
        int grp = idx >> 9, off = idx & 511;
        int g = grp / 18, ks = grp - g * 18;
        int l = off >> 3, e = off & 7;
        int n = g * 16 + (l & 15);
        int k = ks * 32 + ((l >> 4) << 3) + e;
        float v = 0.f;
        if (k < 550) { int c = k / 25; v = c1w[n * 550 + k] * (1.0f / MAXV[c]); }
        W1F[idx] = f2bf(v);
    } else if (idx < 221184) {               // W2F: grp = g*36+ks; k=p*128+ic
        int j = idx - 73728;
        int grp = j >> 9, off = j & 511;
        int g = grp / 36, ks = grp - g * 36;
        int l = off >> 3, e = off & 7;
        int oc = g * 16 + (l & 15);
        int k = ks * 32 + ((l >> 4) << 3) + e;
        W2F[j] = f2bf(c2w[oc * 1152 + (k & 127) * 9 + (k >> 7)]);
    } else if (idx < 253952) {               // FCF: grp = g*4+kc
        int j = idx - 221184;
        int grp = j >> 9, off = j & 511;
        int g = grp >> 2, kc = grp & 3;
        int l = off >> 3, e = off & 7;
        int n = g * 16 + (l & 15);
        int k = kc * 32 + ((l >> 4) << 3) + e;
        FCF[j] = f2bf(fcw[n * 128 + k]);
    } else if (idx < 262144) {               // SELFF
        int j = idx - 253952;
        int g = j >> 9, off = j & 511;
        int l = off >> 3, e = off & 7;
        int n = g * 16 + (l & 15);
        int k = ((l >> 4) << 3) + e;
        float v = (k < 22) ? sfw[n * 22 + k] * (1.0f / MAXV[k]) : 0.f;
        SELFF[j] = f2bf(v);
    } else if (idx < 278528) {               // HEADF: grp = g*16+ks
        int j = idx - 262144;
        int grp = j >> 9, off = j & 511;
        int g = grp >> 4, ks = grp & 15;
        int l = off >> 3, e = off & 7;
        int n = g * 16 + (l & 15);
        int k = ks * 32 + ((l >> 4) << 3) + e;
        float v = 0.f;
        if (n < 9) v = a0w[n * 512 + k];
        else if (n < 19) v = a1w[(n - 9) * 512 + k];
        else if (n == 19) v = vw[k];
        HEADF[j] = f2bf(v);
    } else if (idx < 279328) {               // BIAS[800]
        int j = idx - 278528;
        float v = 0.f;
        if (j < 128) v = c1b[j];
        else if (j < 256) v = c2b[j - 128];
        else if (j < 512) v = fcb[j - 256];
        else if (j < 768) v = sfb[j - 512];
        else {
            int j2 = j - 768;
            if (j2 < 9) v = a0b[j2]; else if (j2 < 19) v = a1b[j2 - 9]; else if (j2 == 19) v = vb[0];
        }
        BIAS[j] = v;
    }
}

// ---------------- K12: 4 samples/WG, stride-552 A (39.9KB), 4 WGs/CU, 1 barrier ----------------
// Wave-private write-order scatter (round-12); stride-552 aliasing killed by zero weights
// (round-14); h1F written DIRECTLY from accumulators in fragment layout (no LDS repack).
__global__ __launch_bounds__(256, 4) void k12_kernel(
    const int* __restrict__ obs, const u16* __restrict__ W1F,
    const float* __restrict__ BIAS, u16* __restrict__ h1F, u16* __restrict__ s22g)
{
    __shared__ __align__(16) u16 A[19968];        // 39,936 B (stride 552 u16/row, linear)
    const int tid = threadIdx.x, w = tid >> 6, l = tid & 63;
    const int s0 = blockIdx.x * 4;

    // prefetch own sample's tokens (4 rounds x 3 ints)
    const int* myobs = obs + (long)(s0 + w) * 600;
    int tk[4][3];
    #pragma unroll
    for (int r = 0; r < 4; ++r) {
        int m = r * 64 + l; int mm = m < 200 ? m : 0;
        tk[r][0] = myobs[mm * 3]; tk[r][1] = myobs[mm * 3 + 1]; tk[r][2] = myobs[mm * 3 + 2];
    }

    // zero own region (wave-private; wave 3 also covers the tail up to 19968)
    {
        short8 z = {0, 0, 0, 0, 0, 0, 0, 0};
        int base = w * 621;                   // 621 short8 = 9 rows x 552 u16
        int cnt = (w == 3) ? 633 : 621;
        for (int i = l; i < cnt; i += 64) *(short8*)(A + (base + i) * 8) = z;
    }
    __builtin_amdgcn_sched_barrier(0);

    #pragma unroll
    for (int r = 0; r < 4; ++r) {
        int m = r * 64 + l;
        int c = tk[r][0], a = tk[r][1], v = tk[r][2];
        c = (c == 255) ? 0 : c; a = (a == 255) ? 0 : a; v = (v == 255) ? 0 : v;
        int xs = (c >> 4) & 15, ys = c & 15;
        int ok = (m < 200) & ((unsigned)a < 22u) & (xs < 11) & (ys < 11);
        if (ok) {
            u16 bv = f2bf((float)v);
            int bcol = a * 25;
            #pragma unroll
            for (int ox = 0; ox < 3; ++ox) {
                int kx = xs - 3 * ox;
                if ((unsigned)kx > 4u) continue;
                #pragma unroll
                for (int oy = 0; oy < 3; ++oy) {
                    int ky = ys - 3 * oy;
                    if ((unsigned)ky > 4u) continue;
                    int row = w * 9 + ox * 3 + oy;
                    A[row * 552 + bcol + kx * 5 + ky] = bv;
                }
            }
        }
        __builtin_amdgcn_sched_barrier(0);    // pin round ordering (cross-round same-address)
    }
    // s22 export straight from A (center cell: row s*9+4, col a*25+12; chan>=22 junk is
    // killed by SELFF's zero columns)
    if (l < 32) {
        int row = w * 9 + 4;
        s22g[(s0 + w) * 32 + l] = A[row * 552 + l * 25 + 12];
    }
    __syncthreads();                          // the ONLY barrier: all A-blocks final

    // ---- GEMM [48(36) x 552(576)] x [576 x 32/wave]: pipelined B, setprio'd ----
    int Aoff[3];
    #pragma unroll
    for (int mt = 0; mt < 3; ++mt) {
        int row = mt * 16 + (l & 15);
        row = row < 36 ? row : 35;
        Aoff[mt] = (row * 552 + ((l >> 4) << 3)) << 1;   // byte offset, linear
    }
    const u16* Wp0 = W1F + ((w * 2 + 0) * 18 << 9) + l * 8;
    const u16* Wp1 = W1F + ((w * 2 + 1) * 18 << 9) + l * 8;

    f32x4 acc[3][2];
    const f32x4 fz = {0.f, 0.f, 0.f, 0.f};
    #pragma unroll
    for (int i = 0; i < 3; ++i) { acc[i][0] = fz; acc[i][1] = fz; }

    short8 cb0 = *(const short8*)(Wp0);
    short8 cb1 = *(const short8*)(Wp1);
    short8 nb0 = *(const short8*)(Wp0 + 512);
    short8 nb1 = *(const short8*)(Wp1 + 512);
    __builtin_amdgcn_s_setprio(1);
    #pragma unroll
    for (int ks = 0; ks < 18; ++ks) {
        short8 t0 = cb0, t1 = cb1;
        if (ks < 16) {
            t0 = *(const short8*)(Wp0 + (ks + 2) * 512);
            t1 = *(const short8*)(Wp1 + (ks + 2) * 512);
        }
        short8 a0 = *(const short8*)((const char*)A + Aoff[0] + ks * 64);
        short8 a1 = *(const short8*)((const char*)A + Aoff[1] + ks * 64);
        short8 a2 = *(const short8*)((const char*)A + Aoff[2] + ks * 64);
        acc[0][0] = MFMA16(a0, cb0, acc[0][0]);
        acc[0][1] = MFMA16(a0, cb1, acc[0][1]);
        acc[1][0] = MFMA16(a1, cb0, acc[1][0]);
        acc[1][1] = MFMA16(a1, cb1, acc[1][1]);
        acc[2][0] = MFMA16(a2, cb0, acc[2][0]);
        acc[2][1] = MFMA16(a2, cb1, acc[2][1]);
        cb0 = nb0; cb1 = nb1; nb0 = t0; nb1 = t1;
    }
    __builtin_amdgcn_s_setprio(0);

    // ---- direct fragment-layout stores from accumulators (no LDS repack, no barrier) ----
    #pragma unroll
    for (int mt = 0; mt < 3; ++mt) {
        #pragma unroll
        for (int nt = 0; nt < 2; ++nt) {
            int col = w * 32 + nt * 16 + (l & 15);
            float bias = BIAS[col];
            #pragma unroll
            for (int r = 0; r < 4; ++r) {
                int row = mt * 16 + ((l >> 4) << 2) + r;
                if (row < 36) {
                    int ds = row / 9;
                    int pos = row - ds * 9;
                    int s = s0 + ds;
                    float v = acc[mt][nt][r] + bias;
                    v = v > 0.f ? v : 0.f;
                    long ad = (long)(s >> 4) * 18432 + (pos * 4 + w) * 512 +
                              (s & 15) * 8 + (((col >> 3) & 3) << 7) + (col & 7);
                    h1F[ad] = f2bf(v);
                }
            }
        }
    }
}

// ---------------- K3a: conv2, 32 samples/WG, grid 512, depth-3 pipeline, no LDS ----------------
__global__ __launch_bounds__(256, 2) void k3a_kernel(
    const u16* __restrict__ h1F, const u16* __restrict__ W2F,
    const float* __restrict__ BIAS, u16* __restrict__ a3F)
{
    const int tid = threadIdx.x, w = tid >> 6, l = tid & 63;
    const int sb = blockIdx.x * 2, s0 = blockIdx.x * 32;
    const float* c2b = BIAS + 128;
    const f32x4 fz = {0.f, 0.f, 0.f, 0.f};
    f32x4 acc[2][2];
    acc[0][0] = fz; acc[0][1] = fz; acc[1][0] = fz; acc[1][1] = fz;

    const u16* A0p = h1F + (long)(sb + 0) * 18432 + l * 8;
    const u16* A1p = h1F + (long)(sb + 1) * 18432 + l * 8;
    const u16* B0p = W2F + ((w * 2 + 0) * 36 << 9) + l * 8;
    const u16* B1p = W2F + ((w * 2 + 1) * 36 << 9) + l * 8;

    short8 ra0[3], ra1[3], rb0[3], rb1[3];
    #pragma unroll
    for (int d = 0; d < 3; ++d) {
        ra0[d] = *(const short8*)(A0p + d * 512);
        ra1[d] = *(const short8*)(A1p + d * 512);
        rb0[d] = *(const short8*)(B0p + d * 512);
        rb1[d] = *(const short8*)(B1p + d * 512);
    }
    __builtin_amdgcn_s_setprio(1);
    #pragma unroll
    for (int ks = 0; ks < 36; ++ks) {
        const int sl = ks % 3;                 // compile-time (fully unrolled)
        short8 a0 = ra0[sl], a1 = ra1[sl], b0 = rb0[sl], b1 = rb1[sl];
        if (ks < 33) {
            ra0[sl] = *(const short8*)(A0p + (ks + 3) * 512);
            ra1[sl] = *(const short8*)(A1p + (ks + 3) * 512);
            rb0[sl] = *(const short8*)(B0p + (ks + 3) * 512);
            rb1[sl] = *(const short8*)(B1p + (ks + 3) * 512);
        }
        acc[0][0] = MFMA16(a0, b0, acc[0][0]);
        acc[0][1] = MFMA16(a0, b1, acc[0][1]);
        acc[1][0] = MFMA16(a1, b0, acc[1][0]);
        acc[1][1] = MFMA16(a1, b1, acc[1][1]);
    }
    __builtin_amdgcn_s_setprio(0);

    // direct fragment stores to a3F (k3b's fc A-operand layout)
    #pragma unroll
    for (int mt = 0; mt < 2; ++mt) {
        #pragma unroll
        for (int nt = 0; nt < 2; ++nt) {
            int col = w * 32 + nt * 16 + (l & 15);
            float bias = c2b[col];
            #pragma unroll
            for (int r = 0; r < 4; ++r) {
                int row = mt * 16 + ((l >> 4) << 2) + r;
                int s = s0 + row;
                float v = acc[mt][nt][r] + bias; v = v > 0.f ? v : 0.f;
                long ad = (long)(s >> 4) * 2048 + (col >> 5) * 512 +
                          (s & 15) * 8 + (((col >> 3) & 3) << 7) + (col & 7);
                a3F[ad] = f2bf(v);
            }
        }
    }
}

// ---------------- K3b: fc + self + heads, 16 samples/WG, grid 1024, 16.6KB LDS ----------------
__global__ __launch_bounds__(256, 4) void k3b_kernel(
    const u16* __restrict__ a3F, const u16* __restrict__ s22g,
    const u16* __restrict__ FCF, const u16* __restrict__ SELFF,
    const u16* __restrict__ HEADF, const float* __restrict__ BIAS,
    float* __restrict__ out, int B)
{
    __shared__ __align__(16) u16 HID[16 * 520];    // 16,640 B
    const int tid = threadIdx.x, w = tid >> 6, l = tid & 63;
    const int s0 = blockIdx.x * 16;
    const float* fcb = BIAS + 256;
    const float* sfb = BIAS + 512;
    const float* hdb = BIAS + 768;
    const f32x4 fz = {0.f, 0.f, 0.f, 0.f};

    // ---- fc: a3F-frags x FCF-frags -> HID cols 256..511 ----
    f32x4 acc8[4];
    #pragma unroll
    for (int j = 0; j < 4; ++j) acc8[j] = fz;
    #pragma unroll
    for (int kc = 0; kc < 4; ++kc) {
        short8 a = *(const short8*)(a3F + (long)blockIdx.x * 2048 + kc * 512 + l * 8);
        #pragma unroll
        for (int nt = 0; nt < 4; ++nt) {
            short8 bf = *(const short8*)(FCF + (((w * 4 + nt) * 4 + kc) << 9) + l * 8);
            acc8[nt] = MFMA16(a, bf, acc8[nt]);
        }
    }
    #pragma unroll
    for (int nt = 0; nt < 4; ++nt) {
        int col = w * 64 + nt * 16 + (l & 15);
        float bias = fcb[col];
        #pragma unroll
        for (int r = 0; r < 4; ++r) {
            int row = ((l >> 4) << 2) + r;
            float v = acc8[nt][r] + bias; v = v > 0.f ? v : 0.f;
            HID[row * 520 + 256 + col] = f2bf(v);
        }
    }

    // ---- self: s22g-frags x SELFF-frags -> HID cols 0..255 ----
    {
        f32x4 acc9[4];
        #pragma unroll
        for (int j = 0; j < 4; ++j) acc9[j] = fz;
        short8 a = *(const short8*)(s22g + (s0 + (l & 15)) * 32 + ((l >> 4) << 3));
        #pragma unroll
        for (int nt = 0; nt < 4; ++nt) {
            short8 bs = *(const short8*)(SELFF + ((w * 4 + nt) << 9) + l * 8);
            acc9[nt] = MFMA16(a, bs, acc9[nt]);
        }
        #pragma unroll
        for (int nt = 0; nt < 4; ++nt) {
            int col = w * 64 + nt * 16 + (l & 15);
            float bias = sfb[col];
            #pragma unroll
            for (int r = 0; r < 4; ++r) {
                int row = ((l >> 4) << 2) + r;
                float v = acc9[nt][r] + bias; v = v > 0.f ? v : 0.f;
                HID[row * 520 + col] = f2bf(v);
            }
        }
    }
    __syncthreads();

    // ---- heads: HID[16][512] x HEADF; waves 0,1 each own one 16-col frag ----
    if (w < 2) {
        f32x4 hacc = fz;
        #pragma unroll
        for (int ks = 0; ks < 16; ++ks) {
            short8 a = *(const short8*)(HID + (l & 15) * 520 + ks * 32 + ((l >> 4) << 3));
            short8 b = *(const short8*)(HEADF + ((w * 16 + ks) << 9) + l * 8);
            hacc = MFMA16(a, b, hacc);
        }
        #pragma unroll
        for (int r = 0; r < 4; ++r) {
            int srow = s0 + ((l >> 4) << 2) + r;
            int col = w * 16 + (l & 15);
            float v = hacc[r] + hdb[col];
            if (col < 9) out[(long)srow * 9 + col] = v;
            else if (col < 19) out[(long)B * 9 + (long)srow * 10 + (col - 9)] = v;
            else if (col == 19) out[(long)B * 19 + srow] = v;
        }
    }
}

extern "C" void kernel_launch(void* const* d_in, const int* in_sizes, int n_in,
                              void* d_out, int out_size, void* d_ws, size_t ws_size,
                              hipStream_t stream)
{
    const int*   obs = (const int*)d_in[0];
    const float* c1w = (const float*)d_in[1];
    const float* c1b = (const float*)d_in[2];
    const float* c2w = (const float*)d_in[3];
    const float* c2b = (const float*)d_in[4];
    const float* fcw = (const float*)d_in[5];
    const float* fcb = (const float*)d_in[6];
    const float* sfw = (const float*)d_in[7];
    const float* sfb = (const float*)d_in[8];
    const float* a0w = (const float*)d_in[9];
    const float* a0b = (const float*)d_in[10];
    const float* a1w = (const float*)d_in[11];
    const float* a1b = (const float*)d_in[12];
    const float* vw  = (const float*)d_in[13];
    const float* vb  = (const float*)d_in[14];
    const int B = in_sizes[0] / 600;   // 16384

    char* ws = (char*)d_ws;
    u16*   W1F   = (u16*)(ws + 0);
    u16*   W2F   = (u16*)(ws + 147456);
    u16*   FCF   = (u16*)(ws + 442368);
    u16*   SELFF = (u16*)(ws + 507904);
    u16*   HEADF = (u16*)(ws + 524288);
    float* BIAS  = (float*)(ws + 557056);
    u16*   s22g  = (u16*)(ws + 560256);
    u16*   h1F   = (u16*)(ws + 560256 + (size_t)B * 64);
    u16*   a3F   = (u16*)(ws + 560256 + (size_t)B * 64 + (size_t)B * 2304);

    prep_kernel<<<1092, 256, 0, stream>>>(c1w, c1b, c2w, c2b, fcw, fcb, sfw, sfb,
                                          a0w, a0b, a1w, a1b, vw, vb,
                                          W1F, W2F, FCF, SELFF, HEADF, BIAS);
    k12_kernel<<<B / 4, 256, 0, stream>>>(obs, W1F, BIAS, h1F, s22g);
    k3a_kernel<<<B / 32, 256, 0, stream>>>(h1F, W2F, BIAS, a3F);
    k3b_kernel<<<B / 16, 256, 0, stream>>>(a3F, s22g, FCF, SELFF, HEADF, BIAS,
                                           (float*)d_out, B);
}

// Round 16
// 68.767 us; speedup vs baseline: 1.0399x; 1.0399x over previous
//
#include <hip/hip_runtime.h>

typedef unsigned short u16;
typedef __attribute__((ext_vector_type(8))) short short8;
typedef __attribute__((ext_vector_type(4))) float f32x4;

#define MFMA16(a, b, c) __builtin_amdgcn_mfma_f32_16x16x32_bf16((a), (b), (c), 0, 0, 0)

__device__ __forceinline__ u16 f2bf(float f) {
    unsigned u = __float_as_uint(f);
    unsigned r = (u + 0x7FFFu + ((u >> 16) & 1u)) >> 16;
    return (u16)r;
}

__device__ const float MAXV[22] = {9.f, 1.f, 1.f, 10.f, 3.f, 254.f, 1.f, 1.f, 235.f, 8.f, 9.f,
                                   250.f, 29.f, 1.f, 1.f, 8.f, 1.f, 1.f, 6.f, 3.f, 1.f, 2.f};

// ---------------- prep: all weights -> bf16 MFMA-fragment layouts, 1/MAX folded ----------------
__global__ void prep_kernel(
    const float* c1w, const float* c1b, const float* c2w, const float* c2b,
    const float* fcw, const float* fcb, const float* sfw, const float* sfb,
    const float* a0w, const float* a0b, const float* a1w, const float* a1b,
    const float* vw, const float* vb,
    u16* W1F, u16* W2F, u16* FCF, u16* SELFF, u16* HEADF, float* BIAS)
{
    int idx = blockIdx.x * 256 + threadIdx.x;
    if (idx < 73728) {                       // W1F: grp = g*18+ks
        int grp = idx >> 9, off = idx & 511;
        int g = grp / 18, ks = grp - g * 18;
        int l = off >> 3, e = off & 7;
        int n = g * 16 + (l & 15);
        int k = ks * 32 + ((l >> 4) << 3) + e;
        float v = 0.f;
        if (k < 550) { int c = k / 25; v = c1w[n * 550 + k] * (1.0f / MAXV[c]); }
        W1F[idx] = f2bf(v);
    } else if (idx < 221184) {               // W2F: grp = g*36+ks; k=p*128+ic
        int j = idx - 73728;
        int grp = j >> 9, off = j & 511;
        int g = grp / 36, ks = grp - g * 36;
        int l = off >> 3, e = off & 7;
        int oc = g * 16 + (l & 15);
        int k = ks * 32 + ((l >> 4) << 3) + e;
        W2F[j] = f2bf(c2w[oc * 1152 + (k & 127) * 9 + (k >> 7)]);
    } else if (idx < 253952) {               // FCF: grp = g*4+kc
        int j = idx - 221184;
        int grp = j >> 9, off = j & 511;
        int g = grp >> 2, kc = grp & 3;
        int l = off >> 3, e = off & 7;
        int n = g * 16 + (l & 15);
        int k = kc * 32 + ((l >> 4) << 3) + e;
        FCF[j] = f2bf(fcw[n * 128 + k]);
    } else if (idx < 262144) {               // SELFF
        int j = idx - 253952;
        int g = j >> 9, off = j & 511;
        int l = off >> 3, e = off & 7;
        int n = g * 16 + (l & 15);
        int k = ((l >> 4) << 3) + e;
        float v = (k < 22) ? sfw[n * 22 + k] * (1.0f / MAXV[k]) : 0.f;
        SELFF[j] = f2bf(v);
    } else if (idx < 278528) {               // HEADF: grp = g*16+ks
        int j = idx - 262144;
        int grp = j >> 9, off = j & 511;
        int g = grp >> 4, ks = grp & 15;
        int l = off >> 3, e = off & 7;
        int n = g * 16 + (l & 15);
        int k = ks * 32 + ((l >> 4) << 3) + e;
        float v = 0.f;
        if (n < 9) v = a0w[n * 512 + k];
        else if (n < 19) v = a1w[(n - 9) * 512 + k];
        else if (n == 19) v = vw[k];
        HEADF[j] = f2bf(v);
    } else if (idx < 279328) {               // BIAS[800]
        int j = idx - 278528;
        float v = 0.f;
        if (j < 128) v = c1b[j];
        else if (j < 256) v = c2b[j - 128];
        else if (j < 512) v = fcb[j - 256];
        else if (j < 768) v = sfb[j - 512];
        else {
            int j2 = j - 768;
            if (j2 < 9) v = a0b[j2]; else if (j2 < 19) v = a1b[j2 - 9]; else if (j2 == 19) v = vb[0];
        }
        BIAS[j] = v;
    }
}

// ---------------- K12: 4 samples/WG, stride-552 A (39.9KB), 4 WGs/CU (round-14 proven) --------
// Wave-private write-order scatter; stride-552 aliasing killed by zero weights; LDS repack +
// coalesced short8 h1F store (round-15 showed per-element stores are slower). B pipeline depth 3.
__global__ __launch_bounds__(256, 4) void k12_kernel(
    const int* __restrict__ obs, const u16* __restrict__ W1F,
    const float* __restrict__ BIAS, u16* __restrict__ h1F, u16* __restrict__ s22g)
{
    __shared__ __align__(16) u16 A[19968];        // 39,936 B (stride 552 u16/row, linear)
    const int tid = threadIdx.x, w = tid >> 6, l = tid & 63;
    const int s0 = blockIdx.x * 4;

    // prefetch own sample's tokens (4 rounds x 3 ints)
    const int* myobs = obs + (long)(s0 + w) * 600;
    int tk[4][3];
    #pragma unroll
    for (int r = 0; r < 4; ++r) {
        int m = r * 64 + l; int mm = m < 200 ? m : 0;
        tk[r][0] = myobs[mm * 3]; tk[r][1] = myobs[mm * 3 + 1]; tk[r][2] = myobs[mm * 3 + 2];
    }

    // zero own region (wave-private; wave 3 also covers the tail up to 19968)
    {
        short8 z = {0, 0, 0, 0, 0, 0, 0, 0};
        int base = w * 621;                   // 621 short8 = 9 rows x 552 u16
        int cnt = (w == 3) ? 633 : 621;
        for (int i = l; i < cnt; i += 64) *(short8*)(A + (base + i) * 8) = z;
    }
    __builtin_amdgcn_sched_barrier(0);

    #pragma unroll
    for (int r = 0; r < 4; ++r) {
        int m = r * 64 + l;
        int c = tk[r][0], a = tk[r][1], v = tk[r][2];
        c = (c == 255) ? 0 : c; a = (a == 255) ? 0 : a; v = (v == 255) ? 0 : v;
        int xs = (c >> 4) & 15, ys = c & 15;
        int ok = (m < 200) & ((unsigned)a < 22u) & (xs < 11) & (ys < 11);
        if (ok) {
            u16 bv = f2bf((float)v);
            int bcol = a * 25;
            #pragma unroll
            for (int ox = 0; ox < 3; ++ox) {
                int kx = xs - 3 * ox;
                if ((unsigned)kx > 4u) continue;
                #pragma unroll
                for (int oy = 0; oy < 3; ++oy) {
                    int ky = ys - 3 * oy;
                    if ((unsigned)ky > 4u) continue;
                    int row = w * 9 + ox * 3 + oy;
                    A[row * 552 + bcol + kx * 5 + ky] = bv;
                }
            }
        }
        __builtin_amdgcn_sched_barrier(0);    // pin round ordering (cross-round same-address)
    }
    // s22 export straight from A (center cell: row s*9+4, col a*25+12; chan>=22 junk is
    // killed by SELFF's zero columns)
    if (l < 32) {
        int row = w * 9 + 4;
        s22g[(s0 + w) * 32 + l] = A[row * 552 + l * 25 + 12];
    }
    __syncthreads();                          // barrier 1: all A-blocks final

    // ---- GEMM [48(36) x 552(576)] x [576 x 32/wave]: depth-3 B pipeline, setprio'd ----
    int Aoff[3];
    #pragma unroll
    for (int mt = 0; mt < 3; ++mt) {
        int row = mt * 16 + (l & 15);
        row = row < 36 ? row : 35;
        Aoff[mt] = (row * 552 + ((l >> 4) << 3)) << 1;   // byte offset, linear
    }
    const u16* Wp0 = W1F + ((w * 2 + 0) * 18 << 9) + l * 8;
    const u16* Wp1 = W1F + ((w * 2 + 1) * 18 << 9) + l * 8;

    f32x4 acc[3][2];
    const f32x4 fz = {0.f, 0.f, 0.f, 0.f};
    #pragma unroll
    for (int i = 0; i < 3; ++i) { acc[i][0] = fz; acc[i][1] = fz; }

    short8 rb0[3], rb1[3];
    #pragma unroll
    for (int d = 0; d < 3; ++d) {
        rb0[d] = *(const short8*)(Wp0 + d * 512);
        rb1[d] = *(const short8*)(Wp1 + d * 512);
    }
    __builtin_amdgcn_s_setprio(1);
    #pragma unroll
    for (int ks = 0; ks < 18; ++ks) {
        const int sl = ks % 3;                // compile-time (fully unrolled)
        short8 b0 = rb0[sl], b1 = rb1[sl];
        if (ks < 15) {
            rb0[sl] = *(const short8*)(Wp0 + (ks + 3) * 512);
            rb1[sl] = *(const short8*)(Wp1 + (ks + 3) * 512);
        }
        short8 a0 = *(const short8*)((const char*)A + Aoff[0] + ks * 64);
        short8 a1 = *(const short8*)((const char*)A + Aoff[1] + ks * 64);
        short8 a2 = *(const short8*)((const char*)A + Aoff[2] + ks * 64);
        acc[0][0] = MFMA16(a0, b0, acc[0][0]);
        acc[0][1] = MFMA16(a0, b1, acc[0][1]);
        acc[1][0] = MFMA16(a1, b0, acc[1][0]);
        acc[1][1] = MFMA16(a1, b1, acc[1][1]);
        acc[2][0] = MFMA16(a2, b0, acc[2][0]);
        acc[2][1] = MFMA16(a2, b1, acc[2][1]);
    }
    __builtin_amdgcn_s_setprio(0);
    __syncthreads();                          // barrier 2: A reads done, region reusable

    // ---- repack into A region (free), then coalesced h1F fragment store ----
    u16* R = (u16*)A;                         // 4608 u16: R[(ks*16 + hif*4 + ds)*8 + ef]
    #pragma unroll
    for (int mt = 0; mt < 3; ++mt) {
        #pragma unroll
        for (int nt = 0; nt < 2; ++nt) {
            int col = w * 32 + nt * 16 + (l & 15);
            float bias = BIAS[col];
            int hif = nt * 2 + ((l & 15) >> 3);
            int ef = l & 7;
            #pragma unroll
            for (int r = 0; r < 4; ++r) {
                int row = mt * 16 + ((l >> 4) << 2) + r;
                if (row < 36) {
                    int ds = row / 9;
                    int pos = row - ds * 9;
                    int ks = pos * 4 + w;
                    float v = acc[mt][nt][r] + bias;
                    v = v > 0.f ? v : 0.f;
                    R[(ks * 16 + hif * 4 + ds) * 8 + ef] = f2bf(v);
                }
            }
        }
    }
    __syncthreads();                          // barrier 3
    {
        const long Cbase = (long)(s0 >> 4) * 18432 + (s0 & 15) * 8;
        #pragma unroll
        for (int q = 0; q < 3; ++q) {
            int slot = tid + q * 256;
            if (slot < 576) {
                int ks = slot >> 4, lf = slot & 15;
                *(short8*)(h1F + Cbase + ks * 512 + (lf >> 2) * 128 + (lf & 3) * 8) =
                    *(const short8*)(R + slot * 8);
            }
        }
    }
}

// ---------------- K3a: conv2, 32 samples/WG, grid 512, depth-3 pipeline, no LDS ----------------
__global__ __launch_bounds__(256, 2) void k3a_kernel(
    const u16* __restrict__ h1F, const u16* __restrict__ W2F,
    const float* __restrict__ BIAS, u16* __restrict__ a3F)
{
    const int tid = threadIdx.x, w = tid >> 6, l = tid & 63;
    const int sb = blockIdx.x * 2, s0 = blockIdx.x * 32;
    const float* c2b = BIAS + 128;
    const f32x4 fz = {0.f, 0.f, 0.f, 0.f};
    f32x4 acc[2][2];
    acc[0][0] = fz; acc[0][1] = fz; acc[1][0] = fz; acc[1][1] = fz;

    const u16* A0p = h1F + (long)(sb + 0) * 18432 + l * 8;
    const u16* A1p = h1F + (long)(sb + 1) * 18432 + l * 8;
    const u16* B0p = W2F + ((w * 2 + 0) * 36 << 9) + l * 8;
    const u16* B1p = W2F + ((w * 2 + 1) * 36 << 9) + l * 8;

    short8 ra0[3], ra1[3], rb0[3], rb1[3];
    #pragma unroll
    for (int d = 0; d < 3; ++d) {
        ra0[d] = *(const short8*)(A0p + d * 512);
        ra1[d] = *(const short8*)(A1p + d * 512);
        rb0[d] = *(const short8*)(B0p + d * 512);
        rb1[d] = *(const short8*)(B1p + d * 512);
    }
    __builtin_amdgcn_s_setprio(1);
    #pragma unroll
    for (int ks = 0; ks < 36; ++ks) {
        const int sl = ks % 3;                 // compile-time (fully unrolled)
        short8 a0 = ra0[sl], a1 = ra1[sl], b0 = rb0[sl], b1 = rb1[sl];
        if (ks < 33) {
            ra0[sl] = *(const short8*)(A0p + (ks + 3) * 512);
            ra1[sl] = *(const short8*)(A1p + (ks + 3) * 512);
            rb0[sl] = *(const short8*)(B0p + (ks + 3) * 512);
            rb1[sl] = *(const short8*)(B1p + (ks + 3) * 512);
        }
        acc[0][0] = MFMA16(a0, b0, acc[0][0]);
        acc[0][1] = MFMA16(a0, b1, acc[0][1]);
        acc[1][0] = MFMA16(a1, b0, acc[1][0]);
        acc[1][1] = MFMA16(a1, b1, acc[1][1]);
    }
    __builtin_amdgcn_s_setprio(0);

    // direct fragment stores to a3F (k3b's fc A-operand layout)
    #pragma unroll
    for (int mt = 0; mt < 2; ++mt) {
        #pragma unroll
        for (int nt = 0; nt < 2; ++nt) {
            int col = w * 32 + nt * 16 + (l & 15);
            float bias = c2b[col];
            #pragma unroll
            for (int r = 0; r < 4; ++r) {
                int row = mt * 16 + ((l >> 4) << 2) + r;
                int s = s0 + row;
                float v = acc[mt][nt][r] + bias; v = v > 0.f ? v : 0.f;
                long ad = (long)(s >> 4) * 2048 + (col >> 5) * 512 +
                          (s & 15) * 8 + (((col >> 3) & 3) << 7) + (col & 7);
                a3F[ad] = f2bf(v);
            }
        }
    }
}

// ---------------- K3b: fc + self + heads, 16 samples/WG, grid 1024, 16.6KB LDS ----------------
__global__ __launch_bounds__(256, 4) void k3b_kernel(
    const u16* __restrict__ a3F, const u16* __restrict__ s22g,
    const u16* __restrict__ FCF, const u16* __restrict__ SELFF,
    const u16* __restrict__ HEADF, const float* __restrict__ BIAS,
    float* __restrict__ out, int B)
{
    __shared__ __align__(16) u16 HID[16 * 520];    // 16,640 B
    const int tid = threadIdx.x, w = tid >> 6, l = tid & 63;
    const int s0 = blockIdx.x * 16;
    const float* fcb = BIAS + 256;
    const float* sfb = BIAS + 512;
    const float* hdb = BIAS + 768;
    const f32x4 fz = {0.f, 0.f, 0.f, 0.f};

    // ---- fc: a3F-frags x FCF-frags -> HID cols 256..511 ----
    f32x4 acc8[4];
    #pragma unroll
    for (int j = 0; j < 4; ++j) acc8[j] = fz;
    #pragma unroll
    for (int kc = 0; kc < 4; ++kc) {
        short8 a = *(const short8*)(a3F + (long)blockIdx.x * 2048 + kc * 512 + l * 8);
        #pragma unroll
        for (int nt = 0; nt < 4; ++nt) {
            short8 bf = *(const short8*)(FCF + (((w * 4 + nt) * 4 + kc) << 9) + l * 8);
            acc8[nt] = MFMA16(a, bf, acc8[nt]);
        }
    }
    #pragma unroll
    for (int nt = 0; nt < 4; ++nt) {
        int col = w * 64 + nt * 16 + (l & 15);
        float bias = fcb[col];
        #pragma unroll
        for (int r = 0; r < 4; ++r) {
            int row = ((l >> 4) << 2) + r;
            float v = acc8[nt][r] + bias; v = v > 0.f ? v : 0.f;
            HID[row * 520 + 256 + col] = f2bf(v);
        }
    }

    // ---- self: s22g-frags x SELFF-frags -> HID cols 0..255 ----
    {
        f32x4 acc9[4];
        #pragma unroll
        for (int j = 0; j < 4; ++j) acc9[j] = fz;
        short8 a = *(const short8*)(s22g + (s0 + (l & 15)) * 32 + ((l >> 4) << 3));
        #pragma unroll
        for (int nt = 0; nt < 4; ++nt) {
            short8 bs = *(const short8*)(SELFF + ((w * 4 + nt) << 9) + l * 8);
            acc9[nt] = MFMA16(a, bs, acc9[nt]);
        }
        #pragma unroll
        for (int nt = 0; nt < 4; ++nt) {
            int col = w * 64 + nt * 16 + (l & 15);
            float bias = sfb[col];
            #pragma unroll
            for (int r = 0; r < 4; ++r) {
                int row = ((l >> 4) << 2) + r;
                float v = acc9[nt][r] + bias; v = v > 0.f ? v : 0.f;
                HID[row * 520 + col] = f2bf(v);
            }
        }
    }
    __syncthreads();

    // ---- heads: HID[16][512] x HEADF; waves 0,1 each own one 16-col frag ----
    if (w < 2) {
        f32x4 hacc = fz;
        #pragma unroll
        for (int ks = 0; ks < 16; ++ks) {
            short8 a = *(const short8*)(HID + (l & 15) * 520 + ks * 32 + ((l >> 4) << 3));
            short8 b = *(const short8*)(HEADF + ((w * 16 + ks) << 9) + l * 8);
            hacc = MFMA16(a, b, hacc);
        }
        #pragma unroll
        for (int r = 0; r < 4; ++r) {
            int srow = s0 + ((l >> 4) << 2) + r;
            int col = w * 16 + (l & 15);
            float v = hacc[r] + hdb[col];
            if (col < 9) out[(long)srow * 9 + col] = v;
            else if (col < 19) out[(long)B * 9 + (long)srow * 10 + (col - 9)] = v;
            else if (col == 19) out[(long)B * 19 + srow] = v;
        }
    }
}

extern "C" void kernel_launch(void* const* d_in, const int* in_sizes, int n_in,
                              void* d_out, int out_size, void* d_ws, size_t ws_size,
                              hipStream_t stream)
{
    const int*   obs = (const int*)d_in[0];
    const float* c1w = (const float*)d_in[1];
    const float* c1b = (const float*)d_in[2];
    const float* c2w = (const float*)d_in[3];
    const float* c2b = (const float*)d_in[4];
    const float* fcw = (const float*)d_in[5];
    const float* fcb = (const float*)d_in[6];
    const float* sfw = (const float*)d_in[7];
    const float* sfb = (const float*)d_in[8];
    const float* a0w = (const float*)d_in[9];
    const float* a0b = (const float*)d_in[10];
    const float* a1w = (const float*)d_in[11];
    const float* a1b = (const float*)d_in[12];
    const float* vw  = (const float*)d_in[13];
    const float* vb  = (const float*)d_in[14];
    const int B = in_sizes[0] / 600;   // 16384

    char* ws = (char*)d_ws;
    u16*   W1F   = (u16*)(ws + 0);
    u16*   W2F   = (u16*)(ws + 147456);
    u16*   FCF   = (u16*)(ws + 442368);
    u16*   SELFF = (u16*)(ws + 507904);
    u16*   HEADF = (u16*)(ws + 524288);
    float* BIAS  = (float*)(ws + 557056);
    u16*   s22g  = (u16*)(ws + 560256);
    u16*   h1F   = (u16*)(ws + 560256 + (size_t)B * 64);
    u16*   a3F   = (u16*)(ws + 560256 + (size_t)B * 64 + (size_t)B * 2304);

    prep_kernel<<<1092, 256, 0, stream>>>(c1w, c1b, c2w, c2b, fcw, fcb, sfw, sfb,
                                          a0w, a0b, a1w, a1b, vw, vb,
                                          W1F, W2F, FCF, SELFF, HEADF, BIAS);
    k12_kernel<<<B / 4, 256, 0, stream>>>(obs, W1F, BIAS, h1F, s22g);
    k3a_kernel<<<B / 32, 256, 0, stream>>>(h1F, W2F, BIAS, a3F);
    k3b_kernel<<<B / 16, 256, 0, stream>>>(a3F, s22g, FCF, SELFF, HEADF, BIAS,
                                           (float*)d_out, B);
}

// Round 17
// 64.030 us; speedup vs baseline: 1.1169x; 1.0740x over previous
//
#include <hip/hip_runtime.h>

typedef unsigned short u16;
typedef __attribute__((ext_vector_type(8))) short short8;
typedef __attribute__((ext_vector_type(4))) float f32x4;

#define MFMA16(a, b, c) __builtin_amdgcn_mfma_f32_16x16x32_bf16((a), (b), (c), 0, 0, 0)

__device__ __forceinline__ u16 f2bf(float f) {
    unsigned u = __float_as_uint(f);
    unsigned r = (u + 0x7FFFu + ((u >> 16) & 1u)) >> 16;
    return (u16)r;
}

__device__ const float MAXV[22] = {9.f, 1.f, 1.f, 10.f, 3.f, 254.f, 1.f, 1.f, 235.f, 8.f, 9.f,
                                   250.f, 29.f, 1.f, 1.f, 8.f, 1.f, 1.f, 6.f, 3.f, 1.f, 2.f};

// ---------------- prep: all weights -> bf16 MFMA-fragment layouts, 1/MAX folded ----------------
__global__ void prep_kernel(
    const float* c1w, const float* c1b, const float* c2w, const float* c2b,
    const float* fcw, const float* fcb, const float* sfw, const float* sfb,
    const float* a0w, const float* a0b, const float* a1w, const float* a1b,
    const float* vw, const float* vb,
    u16* W1F, u16* W2F, u16* FCF, u16* SELFF, u16* HEADF, float* BIAS)
{
    int idx = blockIdx.x * 256 + threadIdx.x;
    if (idx < 73728) {                       // W1F: grp = g*18+ks
        int grp = idx >> 9, off = idx & 511;
        int g = grp / 18, ks = grp - g * 18;
        int l = off >> 3, e = off & 7;
        int n = g * 16 + (l & 15);
        int k = ks * 32 + ((l >> 4) << 3) + e;
        float v = 0.f;
        if (k < 550) { int c = k / 25; v = c1w[n * 550 + k] * (1.0f / MAXV[c]); }
        W1F[idx] = f2bf(v);
    } else if (idx < 221184) {               // W2F: grp = g*36+ks; k=p*128+ic
        int j = idx - 73728;
        int grp = j >> 9, off = j & 511;
        int g = grp / 36, ks = grp - g * 36;
        int l = off >> 3, e = off & 7;
        int oc = g * 16 + (l & 15);
        int k = ks * 32 + ((l >> 4) << 3) + e;
        W2F[j] = f2bf(c2w[oc * 1152 + (k & 127) * 9 + (k >> 7)]);
    } else if (idx < 253952) {               // FCF: grp = g*4+kc
        int j = idx - 221184;
        int grp = j >> 9, off = j & 511;
        int g = grp >> 2, kc = grp & 3;
        int l = off >> 3, e = off & 7;
        int n = g * 16 + (l & 15);
        int k = kc * 32 + ((l >> 4) << 3) + e;
        FCF[j] = f2bf(fcw[n * 128 + k]);
    } else if (idx < 262144) {               // SELFF
        int j = idx - 253952;
        int g = j >> 9, off = j & 511;
        int l = off >> 3, e = off & 7;
        int n = g * 16 + (l & 15);
        int k = ((l >> 4) << 3) + e;
        float v = (k < 22) ? sfw[n * 22 + k] * (1.0f / MAXV[k]) : 0.f;
        SELFF[j] = f2bf(v);
    } else if (idx < 278528) {               // HEADF: grp = g*16+ks
        int j = idx - 262144;
        int grp = j >> 9, off = j & 511;
        int g = grp >> 4, ks = grp & 15;
        int l = off >> 3, e = off & 7;
        int n = g * 16 + (l & 15);
        int k = ks * 32 + ((l >> 4) << 3) + e;
        float v = 0.f;
        if (n < 9) v = a0w[n * 512 + k];
        else if (n < 19) v = a1w[(n - 9) * 512 + k];
        else if (n == 19) v = vw[k];
        HEADF[j] = f2bf(v);
    } else if (idx < 279328) {               // BIAS[800]
        int j = idx - 278528;
        float v = 0.f;
        if (j < 128) v = c1b[j];
        else if (j < 256) v = c2b[j - 128];
        else if (j < 512) v = fcb[j - 256];
        else if (j < 768) v = sfb[j - 512];
        else {
            int j2 = j - 768;
            if (j2 < 9) v = a0b[j2]; else if (j2 < 19) v = a1b[j2 - 9]; else if (j2 == 19) v = vb[0];
        }
        BIAS[j] = v;
    }
}

// ---------------- K12: 4 samples/WG, stride-552 A (39.9KB), 4 WGs/CU (round-16 proven) --------
__global__ __launch_bounds__(256, 4) void k12_kernel(
    const int* __restrict__ obs, const u16* __restrict__ W1F,
    const float* __restrict__ BIAS, u16* __restrict__ h1F, u16* __restrict__ s22g)
{
    __shared__ __align__(16) u16 A[19968];        // 39,936 B (stride 552 u16/row, linear)
    const int tid = threadIdx.x, w = tid >> 6, l = tid & 63;
    const int s0 = blockIdx.x * 4;

    // prefetch own sample's tokens (4 rounds x 3 ints)
    const int* myobs = obs + (long)(s0 + w) * 600;
    int tk[4][3];
    #pragma unroll
    for (int r = 0; r < 4; ++r) {
        int m = r * 64 + l; int mm = m < 200 ? m : 0;
        tk[r][0] = myobs[mm * 3]; tk[r][1] = myobs[mm * 3 + 1]; tk[r][2] = myobs[mm * 3 + 2];
    }

    // zero own region (wave-private; wave 3 also covers the tail up to 19968)
    {
        short8 z = {0, 0, 0, 0, 0, 0, 0, 0};
        int base = w * 621;                   // 621 short8 = 9 rows x 552 u16
        int cnt = (w == 3) ? 633 : 621;
        for (int i = l; i < cnt; i += 64) *(short8*)(A + (base + i) * 8) = z;
    }
    __builtin_amdgcn_sched_barrier(0);

    #pragma unroll
    for (int r = 0; r < 4; ++r) {
        int m = r * 64 + l;
        int c = tk[r][0], a = tk[r][1], v = tk[r][2];
        c = (c == 255) ? 0 : c; a = (a == 255) ? 0 : a; v = (v == 255) ? 0 : v;
        int xs = (c >> 4) & 15, ys = c & 15;
        int ok = (m < 200) & ((unsigned)a < 22u) & (xs < 11) & (ys < 11);
        if (ok) {
            u16 bv = f2bf((float)v);
            int bcol = a * 25;
            #pragma unroll
            for (int ox = 0; ox < 3; ++ox) {
                int kx = xs - 3 * ox;
                if ((unsigned)kx > 4u) continue;
                #pragma unroll
                for (int oy = 0; oy < 3; ++oy) {
                    int ky = ys - 3 * oy;
                    if ((unsigned)ky > 4u) continue;
                    int row = w * 9 + ox * 3 + oy;
                    A[row * 552 + bcol + kx * 5 + ky] = bv;
                }
            }
        }
        __builtin_amdgcn_sched_barrier(0);    // pin round ordering (cross-round same-address)
    }
    // s22 export straight from A (center cell: row s*9+4, col a*25+12)
    if (l < 32) {
        int row = w * 9 + 4;
        s22g[(s0 + w) * 32 + l] = A[row * 552 + l * 25 + 12];
    }
    __syncthreads();                          // barrier 1: all A-blocks final

    // ---- GEMM [48(36) x 552(576)] x [576 x 32/wave]: depth-3 B pipeline, setprio'd ----
    int Aoff[3];
    #pragma unroll
    for (int mt = 0; mt < 3; ++mt) {
        int row = mt * 16 + (l & 15);
        row = row < 36 ? row : 35;
        Aoff[mt] = (row * 552 + ((l >> 4) << 3)) << 1;   // byte offset, linear
    }
    const u16* Wp0 = W1F + ((w * 2 + 0) * 18 << 9) + l * 8;
    const u16* Wp1 = W1F + ((w * 2 + 1) * 18 << 9) + l * 8;

    f32x4 acc[3][2];
    const f32x4 fz = {0.f, 0.f, 0.f, 0.f};
    #pragma unroll
    for (int i = 0; i < 3; ++i) { acc[i][0] = fz; acc[i][1] = fz; }

    short8 rb0[3], rb1[3];
    #pragma unroll
    for (int d = 0; d < 3; ++d) {
        rb0[d] = *(const short8*)(Wp0 + d * 512);
        rb1[d] = *(const short8*)(Wp1 + d * 512);
    }
    __builtin_amdgcn_s_setprio(1);
    #pragma unroll
    for (int ks = 0; ks < 18; ++ks) {
        const int sl = ks % 3;                // compile-time (fully unrolled)
        short8 b0 = rb0[sl], b1 = rb1[sl];
        if (ks < 15) {
            rb0[sl] = *(const short8*)(Wp0 + (ks + 3) * 512);
            rb1[sl] = *(const short8*)(Wp1 + (ks + 3) * 512);
        }
        short8 a0 = *(const short8*)((const char*)A + Aoff[0] + ks * 64);
        short8 a1 = *(const short8*)((const char*)A + Aoff[1] + ks * 64);
        short8 a2 = *(const short8*)((const char*)A + Aoff[2] + ks * 64);
        acc[0][0] = MFMA16(a0, b0, acc[0][0]);
        acc[0][1] = MFMA16(a0, b1, acc[0][1]);
        acc[1][0] = MFMA16(a1, b0, acc[1][0]);
        acc[1][1] = MFMA16(a1, b1, acc[1][1]);
        acc[2][0] = MFMA16(a2, b0, acc[2][0]);
        acc[2][1] = MFMA16(a2, b1, acc[2][1]);
    }
    __builtin_amdgcn_s_setprio(0);
    __syncthreads();                          // barrier 2: A reads done, region reusable

    // ---- repack into A region (free), then coalesced h1F fragment store ----
    u16* R = (u16*)A;                         // 4608 u16: R[(ks*16 + hif*4 + ds)*8 + ef]
    #pragma unroll
    for (int mt = 0; mt < 3; ++mt) {
        #pragma unroll
        for (int nt = 0; nt < 2; ++nt) {
            int col = w * 32 + nt * 16 + (l & 15);
            float bias = BIAS[col];
            int hif = nt * 2 + ((l & 15) >> 3);
            int ef = l & 7;
            #pragma unroll
            for (int r = 0; r < 4; ++r) {
                int row = mt * 16 + ((l >> 4) << 2) + r;
                if (row < 36) {
                    int ds = row / 9;
                    int pos = row - ds * 9;
                    int ks = pos * 4 + w;
                    float v = acc[mt][nt][r] + bias;
                    v = v > 0.f ? v : 0.f;
                    R[(ks * 16 + hif * 4 + ds) * 8 + ef] = f2bf(v);
                }
            }
        }
    }
    __syncthreads();                          // barrier 3
    {
        const long Cbase = (long)(s0 >> 4) * 18432 + (s0 & 15) * 8;
        #pragma unroll
        for (int q = 0; q < 3; ++q) {
            int slot = tid + q * 256;
            if (slot < 576) {
                int ks = slot >> 4, lf = slot & 15;
                *(short8*)(h1F + Cbase + ks * 512 + (lf >> 2) * 128 + (lf & 3) * 8) =
                    *(const short8*)(R + slot * 8);
            }
        }
    }
}

// ---------------- K3: conv2 + fc + self + heads, 32 samples/WG, grid 512, 42KB LDS ------------
__global__ __launch_bounds__(256, 2) void k3_kernel(
    const u16* __restrict__ h1F, const u16* __restrict__ s22g,
    const u16* __restrict__ W2F, const u16* __restrict__ FCF,
    const u16* __restrict__ SELFF, const u16* __restrict__ HEADF,
    const float* __restrict__ BIAS, float* __restrict__ out, int B)
{
    __shared__ __align__(16) u16 A3[32 * 136];     //  8,704 B
    __shared__ __align__(16) u16 HID[32 * 520];    // 33,280 B
    const int tid = threadIdx.x, w = tid >> 6, l = tid & 63;
    const int sb = blockIdx.x * 2, s0 = blockIdx.x * 32;
    const float* c2b = BIAS + 128;
    const float* fcb = BIAS + 256;
    const float* sfb = BIAS + 512;
    const float* hdb = BIAS + 768;
    const f32x4 fz = {0.f, 0.f, 0.f, 0.f};

    // ---- conv2: M=32, depth-3 pipeline, no staging (k3a body verbatim) ----
    f32x4 acc[2][2];
    acc[0][0] = fz; acc[0][1] = fz; acc[1][0] = fz; acc[1][1] = fz;

    const u16* A0p = h1F + (long)(sb + 0) * 18432 + l * 8;
    const u16* A1p = h1F + (long)(sb + 1) * 18432 + l * 8;
    const u16* B0p = W2F + ((w * 2 + 0) * 36 << 9) + l * 8;
    const u16* B1p = W2F + ((w * 2 + 1) * 36 << 9) + l * 8;

    short8 ra0[3], ra1[3], rb0[3], rb1[3];
    #pragma unroll
    for (int d = 0; d < 3; ++d) {
        ra0[d] = *(const short8*)(A0p + d * 512);
        ra1[d] = *(const short8*)(A1p + d * 512);
        rb0[d] = *(const short8*)(B0p + d * 512);
        rb1[d] = *(const short8*)(B1p + d * 512);
    }
    __builtin_amdgcn_s_setprio(1);
    #pragma unroll
    for (int ks = 0; ks < 36; ++ks) {
        const int sl = ks % 3;                 // compile-time (fully unrolled)
        short8 a0 = ra0[sl], a1 = ra1[sl], b0 = rb0[sl], b1 = rb1[sl];
        if (ks < 33) {
            ra0[sl] = *(const short8*)(A0p + (ks + 3) * 512);
            ra1[sl] = *(const short8*)(A1p + (ks + 3) * 512);
            rb0[sl] = *(const short8*)(B0p + (ks + 3) * 512);
            rb1[sl] = *(const short8*)(B1p + (ks + 3) * 512);
        }
        acc[0][0] = MFMA16(a0, b0, acc[0][0]);
        acc[0][1] = MFMA16(a0, b1, acc[0][1]);
        acc[1][0] = MFMA16(a1, b0, acc[1][0]);
        acc[1][1] = MFMA16(a1, b1, acc[1][1]);
    }
    __builtin_amdgcn_s_setprio(0);

    // conv2 out -> LDS A3 row-major (round-6 proven pattern)
    #pragma unroll
    for (int mt = 0; mt < 2; ++mt) {
        #pragma unroll
        for (int nt = 0; nt < 2; ++nt) {
            int col = w * 32 + nt * 16 + (l & 15);
            float bias = c2b[col];
            #pragma unroll
            for (int r = 0; r < 4; ++r) {
                int row = mt * 16 + ((l >> 4) << 2) + r;
                float v = acc[mt][nt][r] + bias; v = v > 0.f ? v : 0.f;
                A3[row * 136 + col] = f2bf(v);
            }
        }
    }
    __syncthreads();                                   // barrier 1: A3 ready

    // ---- fc: A3(LDS, row-major) x FCF-frags -> HID cols 256..511 ----
    f32x4 acc8[2][4];
    #pragma unroll
    for (int i = 0; i < 2; ++i)
        #pragma unroll
        for (int j = 0; j < 4; ++j) acc8[i][j] = fz;
    #pragma unroll
    for (int kc = 0; kc < 4; ++kc) {
        short8 a[2];
        #pragma unroll
        for (int mt = 0; mt < 2; ++mt)
            a[mt] = *(const short8*)(A3 + (mt * 16 + (l & 15)) * 136 + kc * 32 + ((l >> 4) << 3));
        #pragma unroll
        for (int nt = 0; nt < 4; ++nt) {
            short8 bf = *(const short8*)(FCF + (((w * 4 + nt) * 4 + kc) << 9) + l * 8);
            acc8[0][nt] = MFMA16(a[0], bf, acc8[0][nt]);
            acc8[1][nt] = MFMA16(a[1], bf, acc8[1][nt]);
        }
    }
    #pragma unroll
    for (int mt = 0; mt < 2; ++mt)
        #pragma unroll
        for (int nt = 0; nt < 4; ++nt) {
            int col = w * 64 + nt * 16 + (l & 15);
            float bias = fcb[col];
            #pragma unroll
            for (int r = 0; r < 4; ++r) {
                int row = mt * 16 + ((l >> 4) << 2) + r;
                float v = acc8[mt][nt][r] + bias; v = v > 0.f ? v : 0.f;
                HID[row * 520 + 256 + col] = f2bf(v);
            }
        }

    // ---- self: s22g-frags x SELFF-frags -> HID cols 0..255 (round-11 M=32 verbatim) ----
    {
        f32x4 acc9[2][4];
        #pragma unroll
        for (int i = 0; i < 2; ++i)
            #pragma unroll
            for (int j = 0; j < 4; ++j) acc9[i][j] = fz;
        short8 a[2];
        #pragma unroll
        for (int mt = 0; mt < 2; ++mt)
            a[mt] = *(const short8*)(s22g + (s0 + mt * 16 + (l & 15)) * 32 + ((l >> 4) << 3));
        #pragma unroll
        for (int nt = 0; nt < 4; ++nt) {
            short8 bs = *(const short8*)(SELFF + ((w * 4 + nt) << 9) + l * 8);
            acc9[0][nt] = MFMA16(a[0], bs, acc9[0][nt]);
            acc9[1][nt] = MFMA16(a[1], bs, acc9[1][nt]);
        }
        #pragma unroll
        for (int mt = 0; mt < 2; ++mt)
            #pragma unroll
            for (int nt = 0; nt < 4; ++nt) {
                int col = w * 64 + nt * 16 + (l & 15);
                float bias = sfb[col];
                #pragma unroll
                for (int r = 0; r < 4; ++r) {
                    int row = mt * 16 + ((l >> 4) << 2) + r;
                    float v = acc9[mt][nt][r] + bias; v = v > 0.f ? v : 0.f;
                    HID[row * 520 + col] = f2bf(v);
                }
            }
    }
    __syncthreads();                                   // barrier 2: HID ready

    // ---- heads: HID[32][512] x HEADF; wave w: M-tile (w&1), col-frag (w>>1) ----
    {
        f32x4 hacc = fz;
        const int mt = w & 1, ct = w >> 1;
        #pragma unroll
        for (int ks = 0; ks < 16; ++ks) {
            short8 a = *(const short8*)(HID + (mt * 16 + (l & 15)) * 520 + ks * 32 + ((l >> 4) << 3));
            short8 b = *(const short8*)(HEADF + ((ct * 16 + ks) << 9) + l * 8);
            hacc = MFMA16(a, b, hacc);
        }
        #pragma unroll
        for (int r = 0; r < 4; ++r) {
            int srow = s0 + mt * 16 + ((l >> 4) << 2) + r;
            int col = ct * 16 + (l & 15);
            float v = hacc[r] + hdb[col];
            if (col < 9) out[(long)srow * 9 + col] = v;
            else if (col < 19) out[(long)B * 9 + (long)srow * 10 + (col - 9)] = v;
            else if (col == 19) out[(long)B * 19 + srow] = v;
        }
    }
}

extern "C" void kernel_launch(void* const* d_in, const int* in_sizes, int n_in,
                              void* d_out, int out_size, void* d_ws, size_t ws_size,
                              hipStream_t stream)
{
    const int*   obs = (const int*)d_in[0];
    const float* c1w = (const float*)d_in[1];
    const float* c1b = (const float*)d_in[2];
    const float* c2w = (const float*)d_in[3];
    const float* c2b = (const float*)d_in[4];
    const float* fcw = (const float*)d_in[5];
    const float* fcb = (const float*)d_in[6];
    const float* sfw = (const float*)d_in[7];
    const float* sfb = (const float*)d_in[8];
    const float* a0w = (const float*)d_in[9];
    const float* a0b = (const float*)d_in[10];
    const float* a1w = (const float*)d_in[11];
    const float* a1b = (const float*)d_in[12];
    const float* vw  = (const float*)d_in[13];
    const float* vb  = (const float*)d_in[14];
    const int B = in_sizes[0] / 600;   // 16384

    char* ws = (char*)d_ws;
    u16*   W1F   = (u16*)(ws + 0);
    u16*   W2F   = (u16*)(ws + 147456);
    u16*   FCF   = (u16*)(ws + 442368);
    u16*   SELFF = (u16*)(ws + 507904);
    u16*   HEADF = (u16*)(ws + 524288);
    float* BIAS  = (float*)(ws + 557056);
    u16*   s22g  = (u16*)(ws + 560256);
    u16*   h1F   = (u16*)(ws + 560256 + (size_t)B * 64);

    prep_kernel<<<1092, 256, 0, stream>>>(c1w, c1b, c2w, c2b, fcw, fcb, sfw, sfb,
                                          a0w, a0b, a1w, a1b, vw, vb,
                                          W1F, W2F, FCF, SELFF, HEADF, BIAS);
    k12_kernel<<<B / 4, 256, 0, stream>>>(obs, W1F, BIAS, h1F, s22g);
    k3_kernel<<<B / 32, 256, 0, stream>>>(h1F, s22g, W2F, FCF, SELFF, HEADF, BIAS,
                                          (float*)d_out, B);
}